// Round 5
// baseline (3927.657 us; speedup 1.0000x reference)
//
#include <hip/hip_runtime.h>
#include <math.h>

// GraphWaveNet forward — Round 5: fully-fused layer GEMM ("k_layer").
//
// M-layout is channels-innermost: m = (bl*Tn + t)*32 + ci, so each 128-row
// tile holds 4 complete channel groups. One k_layer block computes, for its
// (m,n) out tile, all 6 support slices (6 K-loops over K=2048) and after each
// slice applies the 32x32 channel mix as a second MFMA:
//   C-tile (f32 regs) -> per-wave LDS patch Pb[n][ci] (bf16, B-layout)
//   W_s^T (LDS, bf16)  -> A-operand;  D += W_s^T x C   (f32 regs, carried)
// Epilogue: nxt(rmw, pre-initialized by k_gate with bias + W0*xg) += D +
// resid, then BN. No Z buffer, no accum kernel: 3 dispatches per layer.
// skip telescopes (last time step only). End head = MFMA.
//
// Workspace (BL = batches per chunk; BL=16 if ws >= 218,103,808 B else 8):
//   ST    6 x 2048^2 bf16 [S0,S0^2,S1,S1^2,S2,S2^2]^T   @0           50,331,648
//   skip  16x256x2048 f32                               @50,331,648  33,554,432
//   bufA  BL x 13 x 32 x 2048 f32                       @83,886,080  BL*3,407,872
//   bufB  same                                          (adjacent)
//   xg    (BL*Tn*32) x 2048 bf16                        (adjacent)   BL*1,572,864
// Overlays: adp f32 @bufB, Sbf bf16 @bufA (startup);
//           h bf16 @bufA, skipT @bufA+33.5MB, E1bf @ST (post-loop).

#define NNODE 2048
#define NLAYER 8
#define SSTR ((size_t)NNODE * NNODE)

typedef unsigned short u16;
typedef __attribute__((ext_vector_type(8))) short bf16x8;
typedef __attribute__((ext_vector_type(4))) float f32x4;

__device__ __forceinline__ u16 f2bf(float f) {
    unsigned u = __builtin_bit_cast(unsigned, f);
    u += 0x7fffu + ((u >> 16) & 1u);   // round-to-nearest-even
    return (u16)(u >> 16);
}
__device__ __forceinline__ float bf2f(u16 h) {
    unsigned u = ((unsigned)h) << 16;
    return __builtin_bit_cast(float, u);
}

__device__ __forceinline__ void gld16(const void* g, void* l) {
    __builtin_amdgcn_global_load_lds(
        (const __attribute__((address_space(1))) unsigned int*)g,
        (__attribute__((address_space(3))) unsigned int*)l, 16, 0, 0);
}

// ---------------- adp = softmax(relu(nv1 @ nv2), axis=1) ----------------
__global__ __launch_bounds__(256) void k_adp_mm(const float* __restrict__ nv1,
                                                const float* __restrict__ nv2,
                                                float* __restrict__ P) {
    int v = blockIdx.y;
    int w = blockIdx.x * 256 + threadIdx.x;
    float acc = 0.f;
#pragma unroll
    for (int k = 0; k < 10; ++k) acc += nv1[v * 10 + k] * nv2[k * NNODE + w];
    P[(size_t)v * NNODE + w] = acc;
}

__global__ __launch_bounds__(256) void k_softmax(float* __restrict__ P) {
    int v = blockIdx.x, tid = threadIdx.x;
    float* row = P + (size_t)v * NNODE;
    float m = 0.f;
    for (int w = tid; w < NNODE; w += 256) m = fmaxf(m, fmaxf(row[w], 0.f));
#pragma unroll
    for (int off = 32; off > 0; off >>= 1) m = fmaxf(m, __shfl_down(m, off));
    __shared__ float redm[4];
    __shared__ float reds[4];
    int wave = tid >> 6, lane = tid & 63;
    if (lane == 0) redm[wave] = m;
    __syncthreads();
    m = fmaxf(fmaxf(redm[0], redm[1]), fmaxf(redm[2], redm[3]));
    float s = 0.f;
    for (int w = tid; w < NNODE; w += 256) s += expf(fmaxf(row[w], 0.f) - m);
#pragma unroll
    for (int off = 32; off > 0; off >>= 1) s += __shfl_down(s, off);
    if (lane == 0) reds[wave] = s;
    __syncthreads();
    s = reds[0] + reds[1] + reds[2] + reds[3];
    float inv = 1.f / s;
    for (int w = tid; w < NNODE; w += 256) row[w] = expf(fmaxf(row[w], 0.f) - m) * inv;
}

// ---- supports: S_s^T bf16 -> ST slice 2s; straight-cast S bf16 -> Sbf ----
__global__ __launch_bounds__(256) void k_transp(const float* __restrict__ A,
                                                const float* __restrict__ adp,
                                                u16* __restrict__ ST,
                                                u16* __restrict__ Sbf) {
    __shared__ float tile[32][33];
    int s = blockIdx.z;
    const float* src = (s < 2) ? (A + (size_t)s * SSTR) : adp;
    int v0 = blockIdx.y * 32, w0 = blockIdx.x * 32;
    int tx = threadIdx.x & 31, ty = threadIdx.x >> 5;  // 32 x 8
    u16* dst2 = Sbf + (size_t)s * SSTR;
#pragma unroll
    for (int p = 0; p < 4; ++p) {
        float v = src[(size_t)(v0 + ty + p * 8) * NNODE + w0 + tx];
        tile[ty + p * 8][tx] = v;
        dst2[(size_t)(v0 + ty + p * 8) * NNODE + w0 + tx] = f2bf(v);
    }
    __syncthreads();
    u16* dst = ST + (size_t)(2 * s) * SSTR;
#pragma unroll
    for (int p = 0; p < 4; ++p)
        dst[(size_t)(w0 + ty + p * 8) * NNODE + v0 + tx] = f2bf(tile[tx][ty + p * 8]);
}

// ---- generic bf16 MFMA GEMM (startup S^2 only): C[m,n]=sum_k A[m,k]*BT[n,k] ----
__global__ __launch_bounds__(256) void k_gemm_mfma(
    const u16* __restrict__ A, int lda, size_t asstr,
    const u16* __restrict__ BT, size_t bsstr,
    u16* __restrict__ C, int ldc, size_t csstr, int sbase) {
    __shared__ u16 Asl[128 * 32];
    __shared__ u16 Bsl[128 * 32];
    const int tid = threadIdx.x;
    const int wave = tid >> 6, lane = tid & 63;
    const int sidx = sbase + blockIdx.z;
    const u16* Ab = A + sidx * asstr + (size_t)blockIdx.y * 128 * lda;
    const u16* Bb = BT + sidx * bsstr + (size_t)blockIdx.x * 128 * NNODE;
    const int tr = tid >> 2;
    const int tc = (tid & 3) * 8;
    char* AslB = (char*)Asl + wave * 1024;
    char* BslB = (char*)Bsl + wave * 1024;
    const int wm = (wave & 1) * 64, wn = (wave >> 1) * 64;
    const int fr = lane & 15;
    const int fk = (lane >> 4) * 8;
    f32x4 acc[4][4];
#pragma unroll
    for (int i = 0; i < 4; ++i)
#pragma unroll
        for (int j = 0; j < 4; ++j) acc[i][j] = (f32x4){0.f, 0.f, 0.f, 0.f};

    for (int k0 = 0; k0 < 2048; k0 += 32) {
        gld16(Ab + (size_t)tr * lda + k0 + tc, AslB);
        gld16(Ab + (size_t)(tr + 64) * lda + k0 + tc, AslB + 4096);
        gld16(Bb + (size_t)tr * NNODE + k0 + tc, BslB);
        gld16(Bb + (size_t)(tr + 64) * NNODE + k0 + tc, BslB + 4096);
        __syncthreads();
        bf16x8 af[4], bf[4];
#pragma unroll
        for (int i = 0; i < 4; ++i)
            af[i] = *(const bf16x8*)&Asl[(wm + i * 16 + fr) * 32 + fk];
#pragma unroll
        for (int j = 0; j < 4; ++j)
            bf[j] = *(const bf16x8*)&Bsl[(wn + j * 16 + fr) * 32 + fk];
#pragma unroll
        for (int i = 0; i < 4; ++i)
#pragma unroll
            for (int j = 0; j < 4; ++j)
                acc[i][j] = __builtin_amdgcn_mfma_f32_16x16x32_bf16(af[i], bf[j], acc[i][j], 0, 0, 0);
        __syncthreads();
    }
    u16* Cb = C + sidx * csstr + (size_t)(blockIdx.y * 128 + wm) * ldc + blockIdx.x * 128 + wn;
    const int orow = (lane >> 4) * 4;
#pragma unroll
    for (int i = 0; i < 4; ++i)
#pragma unroll
        for (int j = 0; j < 4; ++j)
#pragma unroll
            for (int r = 0; r < 4; ++r)
                Cb[(size_t)(i * 16 + orow + r) * ldc + j * 16 + fr] = f2bf(acc[i][j][r]);
}

// ---- fused layer GEMM: all 6 slices + MFMA channel-mix + resid + BN ----
__global__ __launch_bounds__(256) void k_layer(
    const u16* __restrict__ Xg, const u16* __restrict__ ST,
    const float* __restrict__ gcwl,
    float* __restrict__ nxt, const float* __restrict__ cur,
    int Tn, int d,
    const float* __restrict__ bng, const float* __restrict__ bnb,
    const float* __restrict__ bnm, const float* __restrict__ bnv) {
    __shared__ u16 Asl[128 * 32];
    __shared__ u16 Bsl[128 * 32];
    __shared__ u16 Wl[6][32][40];   // W_s^T[co][ci], padded to 40 (16B-aligned rows)
    __shared__ u16 Pb[4][64][40];   // per-wave C^T patch [n][ci], bf16
    const int tid = threadIdx.x;
    const int wave = tid >> 6, lane = tid & 63;
    // load W_s^T: Wl[s][co][ci] = gcw[co*224 + 32 + 32*s + ci]
    for (int u = tid; u < 6144; u += 256) {
        int s = u >> 10, co = (u >> 5) & 31, ci = u & 31;
        Wl[s][co][ci] = f2bf(gcwl[co * 224 + 32 + s * 32 + ci]);
    }
    const int m0 = blockIdx.y * 128;
    const int n0 = blockIdx.x * 128;
    const int tr = tid >> 2;
    const int tc = (tid & 3) * 8;
    char* AslB = (char*)Asl + wave * 1024;
    char* BslB = (char*)Bsl + wave * 1024;
    const int wm = (wave & 1) * 64, wn = (wave >> 1) * 64;
    const int fr = lane & 15;
    const int fk = (lane >> 4) * 8;
    const int orow = (lane >> 4) * 4;
    const u16* Ab = Xg + (size_t)m0 * 2048;

    f32x4 D[4][4];
#pragma unroll
    for (int i = 0; i < 4; ++i)
#pragma unroll
        for (int j = 0; j < 4; ++j) D[i][j] = (f32x4){0.f, 0.f, 0.f, 0.f};

    for (int s = 0; s < 6; ++s) {
        const u16* Bb = ST + (size_t)s * SSTR + (size_t)n0 * NNODE;
        f32x4 acc[4][4];
#pragma unroll
        for (int i = 0; i < 4; ++i)
#pragma unroll
            for (int j = 0; j < 4; ++j) acc[i][j] = (f32x4){0.f, 0.f, 0.f, 0.f};
        for (int k0 = 0; k0 < 2048; k0 += 32) {
            gld16(Ab + (size_t)tr * 2048 + k0 + tc, AslB);
            gld16(Ab + (size_t)(tr + 64) * 2048 + k0 + tc, AslB + 4096);
            gld16(Bb + (size_t)tr * NNODE + k0 + tc, BslB);
            gld16(Bb + (size_t)(tr + 64) * NNODE + k0 + tc, BslB + 4096);
            __syncthreads();
            bf16x8 af[4], bf[4];
#pragma unroll
            for (int i = 0; i < 4; ++i)
                af[i] = *(const bf16x8*)&Asl[(wm + i * 16 + fr) * 32 + fk];
#pragma unroll
            for (int j = 0; j < 4; ++j)
                bf[j] = *(const bf16x8*)&Bsl[(wn + j * 16 + fr) * 32 + fk];
#pragma unroll
            for (int i = 0; i < 4; ++i)
#pragma unroll
                for (int j = 0; j < 4; ++j)
                    acc[i][j] = __builtin_amdgcn_mfma_f32_16x16x32_bf16(af[i], bf[j], acc[i][j], 0, 0, 0);
            __syncthreads();
        }
        // ---- channel mix via MFMA: D += W_s^T x C, per local group g ----
#pragma unroll
        for (int g = 0; g < 2; ++g) {
#pragma unroll
            for (int ii = 0; ii < 2; ++ii) {
                int i = g * 2 + ii;
#pragma unroll
                for (int j = 0; j < 4; ++j) {
                    unsigned lo = (unsigned)f2bf(acc[i][j][0]) | ((unsigned)f2bf(acc[i][j][1]) << 16);
                    unsigned hi = (unsigned)f2bf(acc[i][j][2]) | ((unsigned)f2bf(acc[i][j][3]) << 16);
                    uint2 pk; pk.x = lo; pk.y = hi;
                    *(uint2*)&Pb[wave][j * 16 + fr][ii * 16 + orow] = pk;
                }
            }
            // wave-private LDS: in-order DS pipeline, compiler inserts waits
            bf16x8 bP[4];
#pragma unroll
            for (int nt = 0; nt < 4; ++nt)
                bP[nt] = *(const bf16x8*)&Pb[wave][nt * 16 + fr][fk];
#pragma unroll
            for (int cc = 0; cc < 2; ++cc) {
                int ct = g * 2 + cc;
                bf16x8 aW = *(const bf16x8*)&Wl[s][cc * 16 + fr][fk];
#pragma unroll
                for (int nt = 0; nt < 4; ++nt)
                    D[ct][nt] = __builtin_amdgcn_mfma_f32_16x16x32_bf16(aW, bP[nt], D[ct][nt], 0, 0, 0);
            }
        }
    }
    // ---- epilogue: v = nxt(bias + W0*xg) + D + resid; BN ----
#pragma unroll
    for (int ct = 0; ct < 4; ++ct) {
#pragma unroll
        for (int r = 0; r < 4; ++r) {
            int m = m0 + wm + ct * 16 + orow + r;
            int gabs = m >> 5;
            int co = m & 31;
            int bl = gabs / Tn;
            int t = gabs - bl * Tn;
            float inv = bng[co] * rsqrtf(bnv[co] + 1e-5f);
            float mu = bnm[co], be = bnb[co];
            const float* rr = cur + ((size_t)((bl * (Tn + d)) + t + d) * 32 + co) * 2048 + n0 + wn;
            float* op = nxt + (size_t)m * 2048 + n0 + wn;
#pragma unroll
            for (int nt = 0; nt < 4; ++nt) {
                int c = nt * 16 + fr;
                float v = op[c] + D[ct][nt][r] + rr[c];
                op[c] = (v - mu) * inv + be;
            }
        }
    }
}

// ---------------- start conv: pad t by 1, 2 -> 32 channels ----------------
// layout: out[(bl*13 + t)*32 + co][n]
__global__ __launch_bounds__(256) void k_start(const float* __restrict__ xin,
                                               const float* __restrict__ sw,
                                               const float* __restrict__ sb,
                                               float* __restrict__ out, int b0) {
    int n = blockIdx.x * 256 + threadIdx.x;
    int t = blockIdx.y;
    int bl = blockIdx.z;
    int b = b0 + bl;
    float x0 = 0.f, x1 = 0.f;
    if (t > 0) {
        x0 = xin[((size_t)(b * 2 + 0) * NNODE + n) * 12 + (t - 1)];
        x1 = xin[((size_t)(b * 2 + 1) * NNODE + n) * 12 + (t - 1)];
    }
#pragma unroll
    for (int co = 0; co < 32; ++co) {
        float v = sw[co * 2 + 0] * x0 + sw[co * 2 + 1] * x1 + sb[co];
        out[((size_t)((bl * 13 + t) * 32 + co)) * NNODE + n] = v;
    }
}

// ------- dilated filter/gate conv + tanh*sigmoid -> bf16 xg; also writes
//         nxt init = gcn_bias + W0 * xg (identity group of the GCN) -------
__global__ __launch_bounds__(256) void k_gate(const float* __restrict__ cur,
                                              u16* __restrict__ xg,
                                              float* __restrict__ nxt,
                                              int T, int Tn, int d,
                                              const float* __restrict__ fw,
                                              const float* __restrict__ fb,
                                              const float* __restrict__ gw,
                                              const float* __restrict__ gb,
                                              const float* __restrict__ gcwl,
                                              const float* __restrict__ gcbl,
                                              int donxt) {
    __shared__ float4 wp[1024];     // [ci*32+co] = {fw0, fw1, gw0, gw1}
    __shared__ float w0[32][33];    // identity-group W: [ci][co']
    int tid = threadIdx.x;
#pragma unroll
    for (int u = 0; u < 4; ++u) {
        int idx = tid + u * 256;
        int ci = idx >> 5, co = idx & 31;
        wp[idx] = make_float4(fw[co * 64 + ci * 2], fw[co * 64 + ci * 2 + 1],
                              gw[co * 64 + ci * 2], gw[co * 64 + ci * 2 + 1]);
        w0[ci][co] = gcwl[co * 224 + ci];
    }
    __syncthreads();
    int n = blockIdx.x * 512 + tid;
    int t = blockIdx.y;
    int bl = blockIdx.z;
    float f0[32], f1[32], g0[32], g1[32];
#pragma unroll
    for (int co = 0; co < 32; ++co) { f0[co] = 0.f; f1[co] = 0.f; g0[co] = 0.f; g1[co] = 0.f; }
    for (int ci = 0; ci < 32; ++ci) {
        size_t ba = ((size_t)((bl * T + t) * 32 + ci)) * NNODE + n;
        size_t bb = ((size_t)((bl * T + t + d) * 32 + ci)) * NNODE + n;
        float xa0 = cur[ba], xa1 = cur[ba + 256];
        float xb0 = cur[bb], xb1 = cur[bb + 256];
#pragma unroll
        for (int co = 0; co < 32; ++co) {
            float4 w = wp[ci * 32 + co];
            f0[co] += w.x * xa0 + w.y * xb0;
            f1[co] += w.x * xa1 + w.y * xb1;
            g0[co] += w.z * xa0 + w.w * xb0;
            g1[co] += w.z * xa1 + w.w * xb1;
        }
    }
#pragma unroll
    for (int co = 0; co < 32; ++co) {
        float fbv = fb[co], gbv = gb[co];
        float a0 = tanhf(f0[co] + fbv) * (1.f / (1.f + expf(-(g0[co] + gbv))));
        float a1 = tanhf(f1[co] + fbv) * (1.f / (1.f + expf(-(g1[co] + gbv))));
        f0[co] = a0; f1[co] = a1;  // keep for W0 mix
        size_t o = ((size_t)((bl * Tn + t) * 32 + co)) * NNODE + n;
        xg[o] = f2bf(a0);
        xg[o + 256] = f2bf(a1);
    }
    if (donxt) {
#pragma unroll
        for (int cop = 0; cop < 32; ++cop) {
            float s0 = gcbl[cop], s1 = s0;
#pragma unroll
            for (int ci = 0; ci < 32; ++ci) {
                float wv = w0[ci][cop];
                s0 += wv * f0[ci];
                s1 += wv * f1[ci];
            }
            size_t o = ((size_t)((bl * Tn + t) * 32 + cop)) * NNODE + n;
            nxt[o] = s0;
            nxt[o + 256] = s1;
        }
    }
}

// ---- skip conv, last time step only; accumulates across layers (f32) ----
__global__ __launch_bounds__(256) void k_skip(const u16* __restrict__ xg,
                                              float* __restrict__ skip, int Tn,
                                              const float* __restrict__ sw,
                                              const float* __restrict__ sb, int b0, int init) {
    __shared__ float wl[256];  // 8 sc rows x 32 ci
    int tid = threadIdx.x;
    int sc0 = blockIdx.y * 8;
    wl[tid] = sw[sc0 * 32 + tid];
    __syncthreads();
    int n = blockIdx.x * 256 + tid;
    int bl = blockIdx.z;
    float acc[8];
#pragma unroll
    for (int j = 0; j < 8; ++j) acc[j] = 0.f;
    size_t rbase = (size_t)((bl * Tn + (Tn - 1)) * 32);
    for (int ci = 0; ci < 32; ci += 4) {
        float v0 = bf2f(xg[(rbase + ci + 0) * NNODE + n]);
        float v1 = bf2f(xg[(rbase + ci + 1) * NNODE + n]);
        float v2 = bf2f(xg[(rbase + ci + 2) * NNODE + n]);
        float v3 = bf2f(xg[(rbase + ci + 3) * NNODE + n]);
#pragma unroll
        for (int j = 0; j < 8; ++j) {
            float4 w = *(const float4*)&wl[j * 32 + ci];
            acc[j] += w.x * v0 + w.y * v1 + w.z * v2 + w.w * v3;
        }
    }
    int b = b0 + bl;
#pragma unroll
    for (int j = 0; j < 8; ++j) {
        size_t o = ((size_t)(b * 256) + sc0 + j) * NNODE + n;
        float val = acc[j] + sb[sc0 + j];
        if (init) skip[o] = val;
        else skip[o] += val;
    }
}

// ---- end head prep: skipT[b][n][sc] = bf16(relu(skip[b][sc][n])) ----
__global__ __launch_bounds__(256) void k_skipT(const float* __restrict__ skip,
                                               u16* __restrict__ skipT) {
    __shared__ float tile[32][33];
    int b = blockIdx.z;
    int n0 = blockIdx.x * 32, c0 = blockIdx.y * 32;
    int tx = threadIdx.x & 31, ty = threadIdx.x >> 5;
#pragma unroll
    for (int p = 0; p < 4; ++p)
        tile[ty + p * 8][tx] = skip[((size_t)b * 256 + c0 + ty + p * 8) * NNODE + n0 + tx];
    __syncthreads();
#pragma unroll
    for (int p = 0; p < 4; ++p)
        skipT[((size_t)b * NNODE + n0 + ty + p * 8) * 256 + c0 + tx] =
            f2bf(fmaxf(tile[tx][ty + p * 8], 0.f));
}

__global__ __launch_bounds__(256) void k_cast(const float* __restrict__ src,
                                              u16* __restrict__ dst) {
    int i = blockIdx.x * 256 + threadIdx.x;
    dst[i] = f2bf(src[i]);
}

// ---- end1 MFMA: h[b][e][n] = relu(E1[e,:] . relu(skip)[b,:,n] + b1[e]) ----
__global__ __launch_bounds__(256) void k_end1m(const u16* __restrict__ E1,
                                               const u16* __restrict__ skT,
                                               const float* __restrict__ bias,
                                               u16* __restrict__ h) {
    __shared__ u16 Asl[128 * 32];
    __shared__ u16 Bsl[128 * 32];
    const int tid = threadIdx.x;
    const int wave = tid >> 6, lane = tid & 63;
    const int b = blockIdx.z;
    const int m0 = blockIdx.y * 128;
    const int n0 = blockIdx.x * 128;
    const int tr = tid >> 2;
    const int tc = (tid & 3) * 8;
    char* AslB = (char*)Asl + wave * 1024;
    char* BslB = (char*)Bsl + wave * 1024;
    const int wm = (wave & 1) * 64, wn = (wave >> 1) * 64;
    const int fr = lane & 15;
    const int fk = (lane >> 4) * 8;
    const u16* Ab = E1 + (size_t)m0 * 256;
    const u16* Bb = skT + ((size_t)b * NNODE + n0) * 256;
    f32x4 acc[4][4];
#pragma unroll
    for (int i = 0; i < 4; ++i)
#pragma unroll
        for (int j = 0; j < 4; ++j) acc[i][j] = (f32x4){0.f, 0.f, 0.f, 0.f};
    for (int k0 = 0; k0 < 256; k0 += 32) {
        gld16(Ab + (size_t)tr * 256 + k0 + tc, AslB);
        gld16(Ab + (size_t)(tr + 64) * 256 + k0 + tc, AslB + 4096);
        gld16(Bb + (size_t)tr * 256 + k0 + tc, BslB);
        gld16(Bb + (size_t)(tr + 64) * 256 + k0 + tc, BslB + 4096);
        __syncthreads();
        bf16x8 af[4], bf[4];
#pragma unroll
        for (int i = 0; i < 4; ++i)
            af[i] = *(const bf16x8*)&Asl[(wm + i * 16 + fr) * 32 + fk];
#pragma unroll
        for (int j = 0; j < 4; ++j)
            bf[j] = *(const bf16x8*)&Bsl[(wn + j * 16 + fr) * 32 + fk];
#pragma unroll
        for (int i = 0; i < 4; ++i)
#pragma unroll
            for (int j = 0; j < 4; ++j)
                acc[i][j] = __builtin_amdgcn_mfma_f32_16x16x32_bf16(af[i], bf[j], acc[i][j], 0, 0, 0);
        __syncthreads();
    }
    const int orow = (lane >> 4) * 4;
#pragma unroll
    for (int i = 0; i < 4; ++i)
#pragma unroll
        for (int r = 0; r < 4; ++r) {
            int m = m0 + wm + i * 16 + orow + r;  // e index, < 512
            float bs = bias[m];
            size_t ob = ((size_t)b * 512 + m) * NNODE + n0 + wn;
#pragma unroll
            for (int j = 0; j < 4; ++j)
                h[ob + j * 16 + fr] = f2bf(fmaxf(acc[i][j][r] + bs, 0.f));
        }
}

__global__ __launch_bounds__(256) void k_end2(const u16* __restrict__ h,
                                              const float* __restrict__ w,
                                              const float* __restrict__ bias,
                                              float* __restrict__ out) {
    __shared__ float wl[512];
    int tid = threadIdx.x;
    int o = blockIdx.y;
    wl[tid] = w[o * 512 + tid];
    wl[tid + 256] = w[o * 512 + tid + 256];
    __syncthreads();
    int n = blockIdx.x * 256 + tid;
    int b = blockIdx.z;
    float acc = 0.f;
    for (int e = 0; e < 512; ++e) acc += wl[e] * bf2f(h[((size_t)(b * 512) + e) * NNODE + n]);
    out[((size_t)(b * 12) + o) * NNODE + n] = acc + bias[o];
}

extern "C" void kernel_launch(void* const* d_in, const int* in_sizes, int n_in,
                              void* d_out, int out_size, void* d_ws, size_t ws_size,
                              hipStream_t stream) {
    const float* x_in = (const float*)d_in[0];
    const float* A    = (const float*)d_in[1];
    const float* nv1  = (const float*)d_in[2];
    const float* nv2  = (const float*)d_in[3];
    const float* fw   = (const float*)d_in[4];
    const float* fb   = (const float*)d_in[5];
    const float* gw   = (const float*)d_in[6];
    const float* gb   = (const float*)d_in[7];
    const float* skw  = (const float*)d_in[8];
    const float* skb  = (const float*)d_in[9];
    const float* gcw  = (const float*)d_in[10];
    const float* gcb  = (const float*)d_in[11];
    const float* bng  = (const float*)d_in[12];
    const float* bnb  = (const float*)d_in[13];
    const float* bnm  = (const float*)d_in[14];
    const float* bnv  = (const float*)d_in[15];
    const float* stw  = (const float*)d_in[16];
    const float* stb  = (const float*)d_in[17];
    const float* e1w  = (const float*)d_in[18];
    const float* e1b  = (const float*)d_in[19];
    const float* e2w  = (const float*)d_in[20];
    const float* e2b  = (const float*)d_in[21];
    (void)in_sizes; (void)n_in; (void)out_size;

    // BL=16 (one chunk) needs 218,103,808 B; BL=8 needs 150,994,944 B.
    const int BL = (ws_size >= 218103808UL) ? 16 : 8;
    const int nch = 16 / BL;
    const size_t bufsz = (size_t)BL * 3407872UL;

    char* base = (char*)d_ws;
    u16*   ST   = (u16*)base;
    float* skip = (float*)(base + 50331648UL);
    float* bufA = (float*)(base + 83886080UL);
    float* bufB = (float*)(base + 83886080UL + bufsz);
    u16*   xg   = (u16*)(base + 83886080UL + 2 * bufsz);
    // startup overlays
    float* adp  = (float*)bufB;
    u16*   Sbf  = (u16*)bufA;
    // post-loop overlays
    u16*   h     = (u16*)(base + 83886080UL);              // 33.5 MB
    u16*   skipT = (u16*)(base + 83886080UL + 33554432UL); // 16.8 MB
    u16*   E1bf  = (u16*)ST;

    k_adp_mm<<<dim3(8, 2048), 256, 0, stream>>>(nv1, nv2, adp);
    k_softmax<<<2048, 256, 0, stream>>>(adp);
    k_transp<<<dim3(64, 64, 3), 256, 0, stream>>>(A, adp, ST, Sbf);
    // (S_s^2)^T: A = S^T (even slices), BT = S (Sbf) -> odd slices
    k_gemm_mfma<<<dim3(16, 16, 3), 256, 0, stream>>>(
        ST, NNODE, 2 * SSTR, Sbf, SSTR, ST + SSTR, NNODE, 2 * SSTR, 0);

    static const int DIL[NLAYER] = {1, 2, 1, 2, 1, 2, 1, 2};
    for (int ch = 0; ch < nch; ++ch) {
        int b0 = ch * BL;
        k_start<<<dim3(8, 13, BL), 256, 0, stream>>>(x_in, stw, stb, bufA, b0);
        float* cur = bufA;
        float* nxt = bufB;
        int T = 13;
        for (int i = 0; i < NLAYER; ++i) {
            int d = DIL[i], Tn = T - d;
            int last = (i == NLAYER - 1);
            k_gate<<<dim3(4, Tn, BL), 256, 0, stream>>>(cur, xg, nxt, T, Tn, d,
                fw + i * 2048, fb + i * 32, gw + i * 2048, gb + i * 32,
                gcw + i * 32 * 224, gcb + i * 32, last ? 0 : 1);
            k_skip<<<dim3(8, 32, BL), 256, 0, stream>>>(xg, skip, Tn,
                skw + i * 256 * 32, skb + i * 256, b0, (i == 0) ? 1 : 0);
            if (last) break;  // layer 7's GCN output is dead
            int MB = BL * Tn / 4;  // M/128, M = BL*Tn*32
            k_layer<<<dim3(16, MB), 256, 0, stream>>>(xg, ST, gcw + i * 32 * 224,
                nxt, cur, Tn, d,
                bng + i * 32, bnb + i * 32, bnm + i * 32, bnv + i * 32);
            float* tmp = cur; cur = nxt; nxt = tmp;
            T = Tn;
        }
    }
    k_cast<<<512, 256, 0, stream>>>(e1w, E1bf);
    k_skipT<<<dim3(64, 8, 16), 256, 0, stream>>>(skip, skipT);
    k_end1m<<<dim3(16, 4, 16), 256, 0, stream>>>(E1bf, skipT, e1b, h);
    k_end2<<<dim3(8, 12, 16), 256, 0, stream>>>(h, e2w, e2b, (float*)d_out);
}

// Round 6
// 3360.545 us; speedup vs baseline: 1.1688x; 1.1688x over previous
//
#include <hip/hip_runtime.h>
#include <math.h>

// GraphWaveNet forward — Round 6: round-4 structure + bf16 residuals +
// 3-slice GEMM passes (2 gemm + 2 accum per layer) + identity-in-gate.
//
// Z = xg @ [S_a|S_b|S_c] (N=6144, grid 48 x M/128), then k_accum applies the
// 32x32 channel mix for the 3 groups, RMW into bf16 nxt; pass 1 adds resid+BN.
// nxt is pre-initialized by k_gate with gcn_bias + W0*xg (identity group).
// ST slice order [S0,S0^2,S1,S1^2,S2,S2^2]^T; slice j <-> W col 32+32j;
// pass p uses slices 3p..3p+2, W cols 32+96p+32g.  All dispatches serialize
// on the single stream -> minimize sum of kernel times + dispatch count.
//
// Workspace (BL=16 if ws >= 239,075,328 B else BL=8):
//   ST    6 x 2048^2 bf16                      @0           50,331,648
//   skip  16x256x2048 f32                      @50,331,648  33,554,432
//   bufA  BL x 32 x 13 x 2048 bf16             @83,886,080  BL*1,703,936
//   bufB  same                                 (adjacent)
//   xg    BL x 32 x 12 x 2048 bf16             (adjacent)   BL*1,572,864
//   Z     (BL*32*12) x 6144 bf16               (adjacent)   BL*4,718,592
// BL=16 total 239,075,328 (< 256 MiB proven available in round 4).
// Overlays: adp f32 @Z, Sbf bf16 @bufA (startup); h bf16 @bufA.., skipT
// @bufA+33.5MB, E1bf @ST (post-loop; skip f32 region untouched).

#define NNODE 2048
#define NLAYER 8
#define SSTR ((size_t)NNODE * NNODE)

typedef unsigned short u16;
typedef __attribute__((ext_vector_type(8))) short bf16x8;
typedef __attribute__((ext_vector_type(4))) float f32x4;

__device__ __forceinline__ u16 f2bf(float f) {
    unsigned u = __builtin_bit_cast(unsigned, f);
    u += 0x7fffu + ((u >> 16) & 1u);   // round-to-nearest-even
    return (u16)(u >> 16);
}
__device__ __forceinline__ float bf2f(u16 h) {
    unsigned u = ((unsigned)h) << 16;
    return __builtin_bit_cast(float, u);
}

__device__ __forceinline__ void gld16(const void* g, void* l) {
    __builtin_amdgcn_global_load_lds(
        (const __attribute__((address_space(1))) unsigned int*)g,
        (__attribute__((address_space(3))) unsigned int*)l, 16, 0, 0);
}

// ---------------- adp = softmax(relu(nv1 @ nv2), axis=1) ----------------
__global__ __launch_bounds__(256) void k_adp_mm(const float* __restrict__ nv1,
                                                const float* __restrict__ nv2,
                                                float* __restrict__ P) {
    int v = blockIdx.y;
    int w = blockIdx.x * 256 + threadIdx.x;
    float acc = 0.f;
#pragma unroll
    for (int k = 0; k < 10; ++k) acc += nv1[v * 10 + k] * nv2[k * NNODE + w];
    P[(size_t)v * NNODE + w] = acc;
}

__global__ __launch_bounds__(256) void k_softmax(float* __restrict__ P) {
    int v = blockIdx.x, tid = threadIdx.x;
    float* row = P + (size_t)v * NNODE;
    float m = 0.f;
    for (int w = tid; w < NNODE; w += 256) m = fmaxf(m, fmaxf(row[w], 0.f));
#pragma unroll
    for (int off = 32; off > 0; off >>= 1) m = fmaxf(m, __shfl_down(m, off));
    __shared__ float redm[4];
    __shared__ float reds[4];
    int wave = tid >> 6, lane = tid & 63;
    if (lane == 0) redm[wave] = m;
    __syncthreads();
    m = fmaxf(fmaxf(redm[0], redm[1]), fmaxf(redm[2], redm[3]));
    float s = 0.f;
    for (int w = tid; w < NNODE; w += 256) s += expf(fmaxf(row[w], 0.f) - m);
#pragma unroll
    for (int off = 32; off > 0; off >>= 1) s += __shfl_down(s, off);
    if (lane == 0) reds[wave] = s;
    __syncthreads();
    s = reds[0] + reds[1] + reds[2] + reds[3];
    float inv = 1.f / s;
    for (int w = tid; w < NNODE; w += 256) row[w] = expf(fmaxf(row[w], 0.f) - m) * inv;
}

// ---- supports: S_s^T bf16 -> ST slice 2s; straight-cast S bf16 -> Sbf ----
__global__ __launch_bounds__(256) void k_transp(const float* __restrict__ A,
                                                const float* __restrict__ adp,
                                                u16* __restrict__ ST,
                                                u16* __restrict__ Sbf) {
    __shared__ float tile[32][33];
    int s = blockIdx.z;
    const float* src = (s < 2) ? (A + (size_t)s * SSTR) : adp;
    int v0 = blockIdx.y * 32, w0 = blockIdx.x * 32;
    int tx = threadIdx.x & 31, ty = threadIdx.x >> 5;  // 32 x 8
    u16* dst2 = Sbf + (size_t)s * SSTR;
#pragma unroll
    for (int p = 0; p < 4; ++p) {
        float v = src[(size_t)(v0 + ty + p * 8) * NNODE + w0 + tx];
        tile[ty + p * 8][tx] = v;
        dst2[(size_t)(v0 + ty + p * 8) * NNODE + w0 + tx] = f2bf(v);
    }
    __syncthreads();
    u16* dst = ST + (size_t)(2 * s) * SSTR;
#pragma unroll
    for (int p = 0; p < 4; ++p)
        dst[(size_t)(w0 + ty + p * 8) * NNODE + v0 + tx] = f2bf(tile[tx][ty + p * 8]);
}

// ---- generic bf16 MFMA GEMM (startup S^2 only): C[m,n]=sum_k A[m,k]*BT[n,k] ----
__global__ __launch_bounds__(256) void k_gemm_mfma(
    const u16* __restrict__ A, int lda, size_t asstr,
    const u16* __restrict__ BT, size_t bsstr,
    u16* __restrict__ C, int ldc, size_t csstr, int sbase) {
    __shared__ u16 Asl[128 * 32];
    __shared__ u16 Bsl[128 * 32];
    const int tid = threadIdx.x;
    const int wave = tid >> 6, lane = tid & 63;
    const int sidx = sbase + blockIdx.z;
    const u16* Ab = A + sidx * asstr + (size_t)blockIdx.y * 128 * lda;
    const u16* Bb = BT + sidx * bsstr + (size_t)blockIdx.x * 128 * NNODE;
    const int tr = tid >> 2;
    const int tc = (tid & 3) * 8;
    char* AslB = (char*)Asl + wave * 1024;
    char* BslB = (char*)Bsl + wave * 1024;
    const int wm = (wave & 1) * 64, wn = (wave >> 1) * 64;
    const int fr = lane & 15;
    const int fk = (lane >> 4) * 8;
    f32x4 acc[4][4];
#pragma unroll
    for (int i = 0; i < 4; ++i)
#pragma unroll
        for (int j = 0; j < 4; ++j) acc[i][j] = (f32x4){0.f, 0.f, 0.f, 0.f};

    for (int k0 = 0; k0 < 2048; k0 += 32) {
        gld16(Ab + (size_t)tr * lda + k0 + tc, AslB);
        gld16(Ab + (size_t)(tr + 64) * lda + k0 + tc, AslB + 4096);
        gld16(Bb + (size_t)tr * NNODE + k0 + tc, BslB);
        gld16(Bb + (size_t)(tr + 64) * NNODE + k0 + tc, BslB + 4096);
        __syncthreads();
        bf16x8 af[4], bf[4];
#pragma unroll
        for (int i = 0; i < 4; ++i)
            af[i] = *(const bf16x8*)&Asl[(wm + i * 16 + fr) * 32 + fk];
#pragma unroll
        for (int j = 0; j < 4; ++j)
            bf[j] = *(const bf16x8*)&Bsl[(wn + j * 16 + fr) * 32 + fk];
#pragma unroll
        for (int i = 0; i < 4; ++i)
#pragma unroll
            for (int j = 0; j < 4; ++j)
                acc[i][j] = __builtin_amdgcn_mfma_f32_16x16x32_bf16(af[i], bf[j], acc[i][j], 0, 0, 0);
        __syncthreads();
    }
    u16* Cb = C + sidx * csstr + (size_t)(blockIdx.y * 128 + wm) * ldc + blockIdx.x * 128 + wn;
    const int orow = (lane >> 4) * 4;
#pragma unroll
    for (int i = 0; i < 4; ++i)
#pragma unroll
        for (int j = 0; j < 4; ++j)
#pragma unroll
            for (int r = 0; r < 4; ++r)
                Cb[(size_t)(i * 16 + orow + r) * ldc + j * 16 + fr] = f2bf(acc[i][j][r]);
}

// ---- Z GEMM: Z[M x 6144] = xg[M x 2048] @ [S_a|S_b|S_c], slices 3p..3p+2 ----
__global__ __launch_bounds__(256) void k_gemmZ(const u16* __restrict__ Xg,
                                               const u16* __restrict__ ST,
                                               u16* __restrict__ Z, int pass) {
    __shared__ u16 Asl[128 * 32];
    __shared__ u16 Bsl[128 * 32];
    const int tid = threadIdx.x;
    const int wave = tid >> 6, lane = tid & 63;
    const int m0 = blockIdx.y * 128;
    const int slice = pass * 3 + (blockIdx.x >> 4);
    const int nIn = (blockIdx.x & 15) * 128;
    const u16* Ab = Xg + (size_t)m0 * 2048;
    const u16* Bb = ST + (size_t)slice * SSTR + (size_t)nIn * NNODE;
    const int tr = tid >> 2;
    const int tc = (tid & 3) * 8;
    char* AslB = (char*)Asl + wave * 1024;
    char* BslB = (char*)Bsl + wave * 1024;
    const int wm = (wave & 1) * 64, wn = (wave >> 1) * 64;
    const int fr = lane & 15;
    const int fk = (lane >> 4) * 8;
    f32x4 acc[4][4];
#pragma unroll
    for (int i = 0; i < 4; ++i)
#pragma unroll
        for (int j = 0; j < 4; ++j) acc[i][j] = (f32x4){0.f, 0.f, 0.f, 0.f};

    for (int k0 = 0; k0 < 2048; k0 += 32) {
        gld16(Ab + (size_t)tr * 2048 + k0 + tc, AslB);
        gld16(Ab + (size_t)(tr + 64) * 2048 + k0 + tc, AslB + 4096);
        gld16(Bb + (size_t)tr * NNODE + k0 + tc, BslB);
        gld16(Bb + (size_t)(tr + 64) * NNODE + k0 + tc, BslB + 4096);
        __syncthreads();
        bf16x8 af[4], bf[4];
#pragma unroll
        for (int i = 0; i < 4; ++i)
            af[i] = *(const bf16x8*)&Asl[(wm + i * 16 + fr) * 32 + fk];
#pragma unroll
        for (int j = 0; j < 4; ++j)
            bf[j] = *(const bf16x8*)&Bsl[(wn + j * 16 + fr) * 32 + fk];
#pragma unroll
        for (int i = 0; i < 4; ++i)
#pragma unroll
            for (int j = 0; j < 4; ++j)
                acc[i][j] = __builtin_amdgcn_mfma_f32_16x16x32_bf16(af[i], bf[j], acc[i][j], 0, 0, 0);
        __syncthreads();
    }
    u16* Cb = Z + (size_t)(m0 + wm) * 6144 + blockIdx.x * 128 + wn;
    const int orow = (lane >> 4) * 4;
#pragma unroll
    for (int i = 0; i < 4; ++i)
#pragma unroll
        for (int j = 0; j < 4; ++j)
#pragma unroll
            for (int r = 0; r < 4; ++r)
                Cb[(size_t)(i * 16 + orow + r) * 6144 + j * 16 + fr] = f2bf(acc[i][j][r]);
}

// ---------------- start conv: pad t by 1, 2 -> 32 channels (bf16 out) ----------------
__global__ __launch_bounds__(256) void k_start(const float* __restrict__ xin,
                                               const float* __restrict__ sw,
                                               const float* __restrict__ sb,
                                               u16* __restrict__ out, int b0) {
    int n = blockIdx.x * 256 + threadIdx.x;
    int t = blockIdx.y;
    int bl = blockIdx.z;
    int b = b0 + bl;
    float x0 = 0.f, x1 = 0.f;
    if (t > 0) {
        x0 = xin[((size_t)(b * 2 + 0) * NNODE + n) * 12 + (t - 1)];
        x1 = xin[((size_t)(b * 2 + 1) * NNODE + n) * 12 + (t - 1)];
    }
#pragma unroll
    for (int co = 0; co < 32; ++co) {
        float v = sw[co * 2 + 0] * x0 + sw[co * 2 + 1] * x1 + sb[co];
        out[((size_t)(bl * 32 + co) * 13 + t) * NNODE + n] = f2bf(v);
    }
}

// ------- dilated filter/gate conv + tanh*sigmoid -> bf16 xg; also writes
//         nxt init = gcn_bias + W0 * xg (identity group), bf16 -------
__global__ __launch_bounds__(256) void k_gate(const u16* __restrict__ cur,
                                              u16* __restrict__ xg,
                                              u16* __restrict__ nxt,
                                              int T, int Tn, int d,
                                              const float* __restrict__ fw,
                                              const float* __restrict__ fb,
                                              const float* __restrict__ gw,
                                              const float* __restrict__ gb,
                                              const float* __restrict__ gcwl,
                                              const float* __restrict__ gcbl,
                                              int donxt) {
    __shared__ float4 wp[1024];     // [ci*32+co] = {fw0, fw1, gw0, gw1}
    __shared__ float w0[32][33];    // identity-group W: [ci][co']
    int tid = threadIdx.x;
#pragma unroll
    for (int u = 0; u < 4; ++u) {
        int idx = tid + u * 256;
        int ci = idx >> 5, co = idx & 31;
        wp[idx] = make_float4(fw[co * 64 + ci * 2], fw[co * 64 + ci * 2 + 1],
                              gw[co * 64 + ci * 2], gw[co * 64 + ci * 2 + 1]);
        w0[ci][co] = gcwl[co * 224 + ci];
    }
    __syncthreads();
    int n = blockIdx.x * 512 + tid;
    int t = blockIdx.y;
    int bl = blockIdx.z;
    float f0[32], f1[32], g0[32], g1[32];
#pragma unroll
    for (int co = 0; co < 32; ++co) { f0[co] = 0.f; f1[co] = 0.f; g0[co] = 0.f; g1[co] = 0.f; }
    for (int ci = 0; ci < 32; ++ci) {
        size_t ba = ((size_t)(bl * 32 + ci) * T + t) * NNODE + n;
        size_t bb = ((size_t)(bl * 32 + ci) * T + t + d) * NNODE + n;
        float xa0 = bf2f(cur[ba]), xa1 = bf2f(cur[ba + 256]);
        float xb0 = bf2f(cur[bb]), xb1 = bf2f(cur[bb + 256]);
#pragma unroll
        for (int co = 0; co < 32; ++co) {
            float4 w = wp[ci * 32 + co];
            f0[co] += w.x * xa0 + w.y * xb0;
            f1[co] += w.x * xa1 + w.y * xb1;
            g0[co] += w.z * xa0 + w.w * xb0;
            g1[co] += w.z * xa1 + w.w * xb1;
        }
    }
#pragma unroll
    for (int co = 0; co < 32; ++co) {
        float fbv = fb[co], gbv = gb[co];
        float a0 = tanhf(f0[co] + fbv) * (1.f / (1.f + expf(-(g0[co] + gbv))));
        float a1 = tanhf(f1[co] + fbv) * (1.f / (1.f + expf(-(g1[co] + gbv))));
        f0[co] = a0; f1[co] = a1;  // keep for identity mix
        size_t o = ((size_t)(bl * 32 + co) * Tn + t) * NNODE + n;
        xg[o] = f2bf(a0);
        xg[o + 256] = f2bf(a1);
    }
    if (donxt) {
#pragma unroll
        for (int cop = 0; cop < 32; ++cop) {
            float s0 = gcbl[cop], s1 = s0;
#pragma unroll
            for (int ci = 0; ci < 32; ++ci) {
                float wv = w0[ci][cop];
                s0 += wv * f0[ci];
                s1 += wv * f1[ci];
            }
            size_t o = ((size_t)(bl * 32 + cop) * Tn + t) * NNODE + n;
            nxt[o] = f2bf(s0);
            nxt[o + 256] = f2bf(s1);
        }
    }
}

// ---- skip conv, last time step only; accumulates across layers (f32) ----
__global__ __launch_bounds__(256) void k_skip(const u16* __restrict__ xg,
                                              float* __restrict__ skip, int Tn,
                                              const float* __restrict__ sw,
                                              const float* __restrict__ sb, int b0, int init) {
    __shared__ float wl[256];  // 8 sc rows x 32 ci
    int tid = threadIdx.x;
    int sc0 = blockIdx.y * 8;
    wl[tid] = sw[sc0 * 32 + tid];
    __syncthreads();
    int n = blockIdx.x * 256 + tid;
    int bl = blockIdx.z;
    float acc[8];
#pragma unroll
    for (int j = 0; j < 8; ++j) acc[j] = 0.f;
    for (int ci = 0; ci < 32; ci += 4) {
        float v0 = bf2f(xg[((size_t)(bl * 32 + ci + 0) * Tn + (Tn - 1)) * NNODE + n]);
        float v1 = bf2f(xg[((size_t)(bl * 32 + ci + 1) * Tn + (Tn - 1)) * NNODE + n]);
        float v2 = bf2f(xg[((size_t)(bl * 32 + ci + 2) * Tn + (Tn - 1)) * NNODE + n]);
        float v3 = bf2f(xg[((size_t)(bl * 32 + ci + 3) * Tn + (Tn - 1)) * NNODE + n]);
#pragma unroll
        for (int j = 0; j < 8; ++j) {
            float4 w = *(const float4*)&wl[j * 32 + ci];
            acc[j] += w.x * v0 + w.y * v1 + w.z * v2 + w.w * v3;
        }
    }
    int b = b0 + bl;
#pragma unroll
    for (int j = 0; j < 8; ++j) {
        size_t o = ((size_t)(b * 256) + sc0 + j) * NNODE + n;
        float val = acc[j] + sb[sc0 + j];
        if (init) skip[o] = val;
        else skip[o] += val;
    }
}

// ---- GCN mix+accumulate: nxt(bf16) += sum_g Wg * Z[:, g*2048..]; pass1 adds resid+BN ----
__global__ __launch_bounds__(256) void k_accum(const u16* __restrict__ Z,
                                               int cbase,
                                               const float* __restrict__ gcnw,
                                               u16* __restrict__ outp,
                                               const u16* __restrict__ resid,
                                               int Tn, int d, int finalf,
                                               const float* __restrict__ bng,
                                               const float* __restrict__ bnb,
                                               const float* __restrict__ bnm,
                                               const float* __restrict__ bnv) {
    __shared__ float wl[3][32][32];  // [g][ci][co]
    int tid = threadIdx.x;
    for (int u = tid; u < 3072; u += 256) {
        int g = u >> 10, ci = (u >> 5) & 31, co = u & 31;
        wl[g][ci][co] = gcnw[co * 224 + cbase + g * 32 + ci];
    }
    __syncthreads();
    int n = blockIdx.x * 512 + tid;  // n and n+256
    int t = blockIdx.y, bl = blockIdx.z;
    float a0[32], a1[32];
#pragma unroll
    for (int co = 0; co < 32; ++co) { a0[co] = 0.f; a1[co] = 0.f; }
    for (int ci = 0; ci < 32; ++ci) {
        size_t m = (size_t)(bl * 32 + ci) * Tn + t;
#pragma unroll
        for (int g = 0; g < 3; ++g) {
            float v0 = bf2f(Z[m * 6144 + g * 2048 + n]);
            float v1 = bf2f(Z[m * 6144 + g * 2048 + n + 256]);
#pragma unroll
            for (int cq = 0; cq < 8; ++cq) {
                float4 w = *(const float4*)&wl[g][ci][cq * 4];
                a0[cq * 4 + 0] += w.x * v0; a1[cq * 4 + 0] += w.x * v1;
                a0[cq * 4 + 1] += w.y * v0; a1[cq * 4 + 1] += w.y * v1;
                a0[cq * 4 + 2] += w.z * v0; a1[cq * 4 + 2] += w.z * v1;
                a0[cq * 4 + 3] += w.w * v0; a1[cq * 4 + 3] += w.w * v1;
            }
        }
    }
#pragma unroll
    for (int co = 0; co < 32; ++co) {
        size_t o = ((size_t)(bl * 32 + co) * Tn + t) * NNODE + n;
        float v0 = bf2f(outp[o]) + a0[co];
        float v1 = bf2f(outp[o + 256]) + a1[co];
        if (finalf) {
            size_t ro = ((size_t)(bl * 32 + co) * (Tn + d) + t + d) * NNODE + n;
            v0 += bf2f(resid[ro]); v1 += bf2f(resid[ro + 256]);
            float inv = bng[co] * rsqrtf(bnv[co] + 1e-5f);
            float mu = bnm[co], be = bnb[co];
            v0 = (v0 - mu) * inv + be;
            v1 = (v1 - mu) * inv + be;
        }
        outp[o] = f2bf(v0); outp[o + 256] = f2bf(v1);
    }
}

// ---- end head prep: skipT[b][n][sc] = bf16(relu(skip[b][sc][n])) ----
__global__ __launch_bounds__(256) void k_skipT(const float* __restrict__ skip,
                                               u16* __restrict__ skipT) {
    __shared__ float tile[32][33];
    int b = blockIdx.z;
    int n0 = blockIdx.x * 32, c0 = blockIdx.y * 32;
    int tx = threadIdx.x & 31, ty = threadIdx.x >> 5;
#pragma unroll
    for (int p = 0; p < 4; ++p)
        tile[ty + p * 8][tx] = skip[((size_t)b * 256 + c0 + ty + p * 8) * NNODE + n0 + tx];
    __syncthreads();
#pragma unroll
    for (int p = 0; p < 4; ++p)
        skipT[((size_t)b * NNODE + n0 + ty + p * 8) * 256 + c0 + tx] =
            f2bf(fmaxf(tile[tx][ty + p * 8], 0.f));
}

__global__ __launch_bounds__(256) void k_cast(const float* __restrict__ src,
                                              u16* __restrict__ dst) {
    int i = blockIdx.x * 256 + threadIdx.x;
    dst[i] = f2bf(src[i]);
}

// ---- end1 MFMA: h[b][e][n] = relu(E1[e,:] . relu(skip)[b,:,n] + b1[e]) ----
__global__ __launch_bounds__(256) void k_end1m(const u16* __restrict__ E1,
                                               const u16* __restrict__ skT,
                                               const float* __restrict__ bias,
                                               u16* __restrict__ h) {
    __shared__ u16 Asl[128 * 32];
    __shared__ u16 Bsl[128 * 32];
    const int tid = threadIdx.x;
    const int wave = tid >> 6, lane = tid & 63;
    const int b = blockIdx.z;
    const int m0 = blockIdx.y * 128;
    const int n0 = blockIdx.x * 128;
    const int tr = tid >> 2;
    const int tc = (tid & 3) * 8;
    char* AslB = (char*)Asl + wave * 1024;
    char* BslB = (char*)Bsl + wave * 1024;
    const int wm = (wave & 1) * 64, wn = (wave >> 1) * 64;
    const int fr = lane & 15;
    const int fk = (lane >> 4) * 8;
    const u16* Ab = E1 + (size_t)m0 * 256;
    const u16* Bb = skT + ((size_t)b * NNODE + n0) * 256;
    f32x4 acc[4][4];
#pragma unroll
    for (int i = 0; i < 4; ++i)
#pragma unroll
        for (int j = 0; j < 4; ++j) acc[i][j] = (f32x4){0.f, 0.f, 0.f, 0.f};
    for (int k0 = 0; k0 < 256; k0 += 32) {
        gld16(Ab + (size_t)tr * 256 + k0 + tc, AslB);
        gld16(Ab + (size_t)(tr + 64) * 256 + k0 + tc, AslB + 4096);
        gld16(Bb + (size_t)tr * 256 + k0 + tc, BslB);
        gld16(Bb + (size_t)(tr + 64) * 256 + k0 + tc, BslB + 4096);
        __syncthreads();
        bf16x8 af[4], bf[4];
#pragma unroll
        for (int i = 0; i < 4; ++i)
            af[i] = *(const bf16x8*)&Asl[(wm + i * 16 + fr) * 32 + fk];
#pragma unroll
        for (int j = 0; j < 4; ++j)
            bf[j] = *(const bf16x8*)&Bsl[(wn + j * 16 + fr) * 32 + fk];
#pragma unroll
        for (int i = 0; i < 4; ++i)
#pragma unroll
            for (int j = 0; j < 4; ++j)
                acc[i][j] = __builtin_amdgcn_mfma_f32_16x16x32_bf16(af[i], bf[j], acc[i][j], 0, 0, 0);
        __syncthreads();
    }
    const int orow = (lane >> 4) * 4;
#pragma unroll
    for (int i = 0; i < 4; ++i)
#pragma unroll
        for (int r = 0; r < 4; ++r) {
            int m = m0 + wm + i * 16 + orow + r;  // e index, < 512
            float bs = bias[m];
            size_t ob = ((size_t)b * 512 + m) * NNODE + n0 + wn;
#pragma unroll
            for (int j = 0; j < 4; ++j)
                h[ob + j * 16 + fr] = f2bf(fmaxf(acc[i][j][r] + bs, 0.f));
        }
}

__global__ __launch_bounds__(256) void k_end2(const u16* __restrict__ h,
                                              const float* __restrict__ w,
                                              const float* __restrict__ bias,
                                              float* __restrict__ out) {
    __shared__ float wl[512];
    int tid = threadIdx.x;
    int o = blockIdx.y;
    wl[tid] = w[o * 512 + tid];
    wl[tid + 256] = w[o * 512 + tid + 256];
    __syncthreads();
    int n = blockIdx.x * 256 + tid;
    int b = blockIdx.z;
    float acc = 0.f;
    for (int e = 0; e < 512; ++e) acc += wl[e] * bf2f(h[((size_t)(b * 512) + e) * NNODE + n]);
    out[((size_t)(b * 12) + o) * NNODE + n] = acc + bias[o];
}

extern "C" void kernel_launch(void* const* d_in, const int* in_sizes, int n_in,
                              void* d_out, int out_size, void* d_ws, size_t ws_size,
                              hipStream_t stream) {
    const float* x_in = (const float*)d_in[0];
    const float* A    = (const float*)d_in[1];
    const float* nv1  = (const float*)d_in[2];
    const float* nv2  = (const float*)d_in[3];
    const float* fw   = (const float*)d_in[4];
    const float* fb   = (const float*)d_in[5];
    const float* gw   = (const float*)d_in[6];
    const float* gb   = (const float*)d_in[7];
    const float* skw  = (const float*)d_in[8];
    const float* skb  = (const float*)d_in[9];
    const float* gcw  = (const float*)d_in[10];
    const float* gcb  = (const float*)d_in[11];
    const float* bng  = (const float*)d_in[12];
    const float* bnb  = (const float*)d_in[13];
    const float* bnm  = (const float*)d_in[14];
    const float* bnv  = (const float*)d_in[15];
    const float* stw  = (const float*)d_in[16];
    const float* stb  = (const float*)d_in[17];
    const float* e1w  = (const float*)d_in[18];
    const float* e1b  = (const float*)d_in[19];
    const float* e2w  = (const float*)d_in[20];
    const float* e2b  = (const float*)d_in[21];
    (void)in_sizes; (void)n_in; (void)out_size;

    // BL=16 (one chunk) needs 239,075,328 B (ws >= 256 MiB proven in round 4);
    // BL=8 fallback needs 161,480,704 B.
    const int BL = (ws_size >= 239075328UL) ? 16 : 8;
    const int nch = 16 / BL;
    const size_t bufsz = (size_t)BL * 1703936UL;  // BL*32*13*2048*2

    char* base = (char*)d_ws;
    u16*   ST   = (u16*)base;
    float* skip = (float*)(base + 50331648UL);
    u16*   bufA = (u16*)(base + 83886080UL);
    u16*   bufB = (u16*)(base + 83886080UL + bufsz);
    u16*   xg   = (u16*)(base + 83886080UL + 2 * bufsz);
    u16*   Z    = (u16*)(base + 83886080UL + 2 * bufsz + (size_t)BL * 1572864UL);
    // startup overlays
    float* adp  = (float*)Z;
    u16*   Sbf  = (u16*)bufA;   // spans bufA(+bufB for BL=8)
    // post-loop overlays
    u16*   h     = (u16*)(base + 83886080UL);              // 33.5 MB
    u16*   skipT = (u16*)(base + 83886080UL + 33554432UL); // 16.8 MB
    u16*   E1bf  = (u16*)ST;

    k_adp_mm<<<dim3(8, 2048), 256, 0, stream>>>(nv1, nv2, adp);
    k_softmax<<<2048, 256, 0, stream>>>(adp);
    k_transp<<<dim3(64, 64, 3), 256, 0, stream>>>(A, adp, ST, Sbf);
    // (S_s^2)^T: A = S^T (even slices), BT = S (Sbf) -> odd slices
    k_gemm_mfma<<<dim3(16, 16, 3), 256, 0, stream>>>(
        ST, NNODE, 2 * SSTR, Sbf, SSTR, ST + SSTR, NNODE, 2 * SSTR, 0);

    static const int DIL[NLAYER] = {1, 2, 1, 2, 1, 2, 1, 2};
    for (int ch = 0; ch < nch; ++ch) {
        int b0 = ch * BL;
        k_start<<<dim3(8, 13, BL), 256, 0, stream>>>(x_in, stw, stb, bufA, b0);
        u16* cur = bufA;
        u16* nxt = bufB;
        int T = 13;
        for (int i = 0; i < NLAYER; ++i) {
            int d = DIL[i], Tn = T - d;
            int last = (i == NLAYER - 1);
            k_gate<<<dim3(4, Tn, BL), 256, 0, stream>>>(cur, xg, nxt, T, Tn, d,
                fw + i * 2048, fb + i * 32, gw + i * 2048, gb + i * 32,
                gcw + i * 32 * 224, gcb + i * 32, last ? 0 : 1);
            k_skip<<<dim3(8, 32, BL), 256, 0, stream>>>(xg, skip, Tn,
                skw + i * 256 * 32, skb + i * 256, b0, (i == 0) ? 1 : 0);
            if (last) break;  // layer 7's GCN output is dead
            int MB = BL * Tn / 4;  // M/128, M = BL*32*Tn
            const float* gcwi = gcw + i * 32 * 224;
            for (int p = 0; p < 2; ++p) {
                k_gemmZ<<<dim3(48, MB), 256, 0, stream>>>(xg, ST, Z, p);
                k_accum<<<dim3(4, Tn, BL), 256, 0, stream>>>(
                    Z, 32 + 96 * p, gcwi, nxt, cur, Tn, d, p,
                    bng + i * 32, bnb + i * 32, bnm + i * 32, bnv + i * 32);
            }
            u16* tmp = cur; cur = nxt; nxt = tmp;
            T = Tn;
        }
    }
    k_cast<<<512, 256, 0, stream>>>(e1w, E1bf);
    k_skipT<<<dim3(64, 8, 16), 256, 0, stream>>>(skip, skipT);
    k_end1m<<<dim3(16, 4, 16), 256, 0, stream>>>(E1bf, skipT, e1b, h);
    k_end2<<<dim3(8, 12, 16), 256, 0, stream>>>(h, e2w, e2b, (float*)d_out);
}